// Round 1
// baseline (134.023 us; speedup 1.0000x reference)
//
#include <hip/hip_runtime.h>
#include <math.h>

#define NATOMS 512
#define TPB 256

// One block per batch element. Thread t handles atoms 2t and 2t+1.
// Single pass: accumulate uncentered sums, apply centroid correction at the end:
//   R = Sum(s d^T) - (Sum s)(Sum d)^T / n
//   sq = Sum|s|^2 + Sum|d|^2 - (|Sum s|^2 + |Sum d|^2)/n
// Then analytic 3x3 symmetric eigen-solve of R^T R (double) for singular values.
__global__ __launch_bounds__(TPB) void kabsch_rmsd_kernel(
    const float* __restrict__ inp,
    const float* __restrict__ tgt,
    const int* __restrict__ num_atoms,
    float* __restrict__ out)
{
    const int b = blockIdx.x;
    const int t = threadIdx.x;
    const int na = num_atoms[b];

    const float* src = inp + (size_t)b * (3 * NATOMS);
    const float* dst = tgt + (size_t)b * (3 * NATOMS);

    // Load atoms 2t, 2t+1 : floats [6t, 6t+6) as three aligned float2s.
    const float2* s2 = (const float2*)src + 3 * t;
    const float2* d2 = (const float2*)dst + 3 * t;
    float2 sA = s2[0], sB = s2[1], sC = s2[2];
    float2 dA = d2[0], dB = d2[1], dC = d2[2];

    float s0x = sA.x, s0y = sA.y, s0z = sB.x;
    float s1x = sB.y, s1y = sC.x, s1z = sC.y;
    float d0x = dA.x, d0y = dA.y, d0z = dB.x;
    float d1x = dB.y, d1y = dC.x, d1z = dC.y;

    const int a0 = 2 * t, a1 = 2 * t + 1;
    if (a0 >= na) { s0x = s0y = s0z = 0.f; d0x = d0y = d0z = 0.f; }
    if (a1 >= na) { s1x = s1y = s1z = 0.f; d1x = d1y = d1z = 0.f; }

    float v[16];
    // M = sum s d^T (row-major: M[i*3+j] = sum s_i d_j)
    v[0]  = s0x * d0x + s1x * d1x;
    v[1]  = s0x * d0y + s1x * d1y;
    v[2]  = s0x * d0z + s1x * d1z;
    v[3]  = s0y * d0x + s1y * d1x;
    v[4]  = s0y * d0y + s1y * d1y;
    v[5]  = s0y * d0z + s1y * d1z;
    v[6]  = s0z * d0x + s1z * d1x;
    v[7]  = s0z * d0y + s1z * d1y;
    v[8]  = s0z * d0z + s1z * d1z;
    // sums
    v[9]  = s0x + s1x;
    v[10] = s0y + s1y;
    v[11] = s0z + s1z;
    v[12] = d0x + d1x;
    v[13] = d0y + d1y;
    v[14] = d0z + d1z;
    // sum of squares (both)
    v[15] = s0x * s0x + s0y * s0y + s0z * s0z
          + s1x * s1x + s1y * s1y + s1z * s1z
          + d0x * d0x + d0y * d0y + d0z * d0z
          + d1x * d1x + d1y * d1y + d1z * d1z;

    // wave-level (64-lane) shuffle reduction
    #pragma unroll
    for (int i = 0; i < 16; ++i) {
        #pragma unroll
        for (int off = 32; off > 0; off >>= 1) {
            v[i] += __shfl_down(v[i], off);
        }
    }

    __shared__ float red[4][16];
    const int wave = t >> 6;
    const int lane = t & 63;
    if (lane == 0) {
        #pragma unroll
        for (int i = 0; i < 16; ++i) red[wave][i] = v[i];
    }
    __syncthreads();

    if (t == 0) {
        double acc[16];
        #pragma unroll
        for (int i = 0; i < 16; ++i) {
            acc[i] = (double)red[0][i] + (double)red[1][i]
                   + (double)red[2][i] + (double)red[3][i];
        }
        const double n = (double)na;
        const double sx = acc[9],  sy = acc[10], sz = acc[11];
        const double tx = acc[12], ty = acc[13], tz = acc[14];

        // centered correlation matrix
        double R[3][3];
        R[0][0] = acc[0] - sx * tx / n;
        R[0][1] = acc[1] - sx * ty / n;
        R[0][2] = acc[2] - sx * tz / n;
        R[1][0] = acc[3] - sy * tx / n;
        R[1][1] = acc[4] - sy * ty / n;
        R[1][2] = acc[5] - sy * tz / n;
        R[2][0] = acc[6] - sz * tx / n;
        R[2][1] = acc[7] - sz * ty / n;
        R[2][2] = acc[8] - sz * tz / n;

        const double sq = acc[15] - (sx * sx + sy * sy + sz * sz
                                   + tx * tx + ty * ty + tz * tz) / n;

        const double detR =
            R[0][0] * (R[1][1] * R[2][2] - R[1][2] * R[2][1])
          - R[0][1] * (R[1][0] * R[2][2] - R[1][2] * R[2][0])
          + R[0][2] * (R[1][0] * R[2][1] - R[1][1] * R[2][0]);

        // A = R^T R (symmetric PSD)
        double A00 = R[0][0]*R[0][0] + R[1][0]*R[1][0] + R[2][0]*R[2][0];
        double A11 = R[0][1]*R[0][1] + R[1][1]*R[1][1] + R[2][1]*R[2][1];
        double A22 = R[0][2]*R[0][2] + R[1][2]*R[1][2] + R[2][2]*R[2][2];
        double A01 = R[0][0]*R[0][1] + R[1][0]*R[1][1] + R[2][0]*R[2][1];
        double A02 = R[0][0]*R[0][2] + R[1][0]*R[1][2] + R[2][0]*R[2][2];
        double A12 = R[0][1]*R[0][2] + R[1][1]*R[1][2] + R[2][1]*R[2][2];

        double e0, e1, e2;  // descending
        const double p1 = A01*A01 + A02*A02 + A12*A12;
        if (p1 < 1e-30) {
            // nearly diagonal: sort diagonal entries
            e0 = A00; e1 = A11; e2 = A22;
            double tmp;
            if (e0 < e1) { tmp = e0; e0 = e1; e1 = tmp; }
            if (e1 < e2) { tmp = e1; e1 = e2; e2 = tmp; }
            if (e0 < e1) { tmp = e0; e0 = e1; e1 = tmp; }
        } else {
            const double q  = (A00 + A11 + A22) / 3.0;
            const double b00 = A00 - q, b11 = A11 - q, b22 = A22 - q;
            const double p2 = b00*b00 + b11*b11 + b22*b22 + 2.0 * p1;
            const double p  = sqrt(p2 / 6.0);
            const double ip = 1.0 / p;
            const double B00 = b00*ip, B11 = b11*ip, B22 = b22*ip;
            const double B01 = A01*ip, B02 = A02*ip, B12 = A12*ip;
            double r = 0.5 * (B00 * (B11 * B22 - B12 * B12)
                            - B01 * (B01 * B22 - B12 * B02)
                            + B02 * (B01 * B12 - B11 * B02));
            if (r < -1.0) r = -1.0;
            if (r >  1.0) r =  1.0;
            const double phi = acos(r) / 3.0;
            e0 = q + 2.0 * p * cos(phi);
            e2 = q + 2.0 * p * cos(phi + 2.0943951023931953);  // +2pi/3
            e1 = 3.0 * q - e0 - e2;
        }

        const double S0 = sqrt(e0 > 0.0 ? e0 : 0.0);
        const double S1 = sqrt(e1 > 0.0 ? e1 : 0.0);
        const double S2 = sqrt(e2 > 0.0 ? e2 : 0.0);
        const double dsgn = (detR > 0.0) ? 1.0 : ((detR < 0.0) ? -1.0 : 0.0);
        const double trace_opt = S0 + S1 + dsgn * S2;

        double msd = (sq - 2.0 * trace_opt) / n;
        if (msd < 0.0) msd = 0.0;
        out[b] = (float)sqrt(msd);
    }
}

extern "C" void kernel_launch(void* const* d_in, const int* in_sizes, int n_in,
                              void* d_out, int out_size, void* d_ws, size_t ws_size,
                              hipStream_t stream) {
    const float* inp = (const float*)d_in[0];
    const float* tgt = (const float*)d_in[1];
    const int* num_atoms = (const int*)d_in[2];
    float* out = (float*)d_out;

    const int B = in_sizes[0] / (3 * NATOMS);
    kabsch_rmsd_kernel<<<B, TPB, 0, stream>>>(inp, tgt, num_atoms, out);
}

// Round 2
// 124.357 us; speedup vs baseline: 1.0777x; 1.0777x over previous
//
#include <hip/hip_runtime.h>
#include <math.h>

#define NATOMS 512
#define TPB 256
#define WPB 4  // waves per block; one wave handles one batch element

// One 64-lane wave per batch element. Lane l handles atoms [8l, 8l+8) :
// floats [24l, 24l+24) = 6 consecutive float4 loads per array.
// Single pass: accumulate uncentered sums; centroid correction at the end:
//   R = Sum(s d^T) - (Sum s)(Sum d)^T / n
//   sq = Sum|s|^2 + Sum|d|^2 - (|Sum s|^2 + |Sum d|^2)/n
// Then analytic 3x3 symmetric eigen-solve of R^T R (double) on lane 0.
__global__ __launch_bounds__(TPB) void kabsch_rmsd_kernel(
    const float* __restrict__ inp,
    const float* __restrict__ tgt,
    const int* __restrict__ num_atoms,
    float* __restrict__ out,
    int B)
{
    const int wave = threadIdx.x >> 6;
    const int lane = threadIdx.x & 63;
    const int b = blockIdx.x * WPB + wave;
    if (b >= B) return;

    const int na = num_atoms[b];

    const float4* s4 = (const float4*)(inp + (size_t)b * (3 * NATOMS)) + 6 * lane;
    const float4* d4 = (const float4*)(tgt + (size_t)b * (3 * NATOMS)) + 6 * lane;

    union U { float4 q[6]; float f[24]; };
    U S, D;
    #pragma unroll
    for (int i = 0; i < 6; ++i) S.q[i] = s4[i];
    #pragma unroll
    for (int i = 0; i < 6; ++i) D.q[i] = d4[i];

    float v[16];
    #pragma unroll
    for (int i = 0; i < 16; ++i) v[i] = 0.f;

    const int base = lane * 8;
    #pragma unroll
    for (int k = 0; k < 8; ++k) {
        const float m = (base + k < na) ? 1.f : 0.f;
        const float sx = S.f[3 * k]     * m;
        const float sy = S.f[3 * k + 1] * m;
        const float sz = S.f[3 * k + 2] * m;
        const float dx = D.f[3 * k]     * m;
        const float dy = D.f[3 * k + 1] * m;
        const float dz = D.f[3 * k + 2] * m;
        v[0]  += sx * dx;  v[1]  += sx * dy;  v[2]  += sx * dz;
        v[3]  += sy * dx;  v[4]  += sy * dy;  v[5]  += sy * dz;
        v[6]  += sz * dx;  v[7]  += sz * dy;  v[8]  += sz * dz;
        v[9]  += sx;  v[10] += sy;  v[11] += sz;
        v[12] += dx;  v[13] += dy;  v[14] += dz;
        v[15] += sx * sx + sy * sy + sz * sz + dx * dx + dy * dy + dz * dz;
    }

    // 64-lane butterfly reduction, no LDS, no barrier
    #pragma unroll
    for (int i = 0; i < 16; ++i) {
        #pragma unroll
        for (int mask = 32; mask > 0; mask >>= 1) {
            v[i] += __shfl_xor(v[i], mask);
        }
    }

    if (lane == 0) {
        const double n = (double)na;
        const double sx = (double)v[9],  sy = (double)v[10], sz = (double)v[11];
        const double tx = (double)v[12], ty = (double)v[13], tz = (double)v[14];

        double R[3][3];
        R[0][0] = (double)v[0] - sx * tx / n;
        R[0][1] = (double)v[1] - sx * ty / n;
        R[0][2] = (double)v[2] - sx * tz / n;
        R[1][0] = (double)v[3] - sy * tx / n;
        R[1][1] = (double)v[4] - sy * ty / n;
        R[1][2] = (double)v[5] - sy * tz / n;
        R[2][0] = (double)v[6] - sz * tx / n;
        R[2][1] = (double)v[7] - sz * ty / n;
        R[2][2] = (double)v[8] - sz * tz / n;

        const double sq = (double)v[15] - (sx * sx + sy * sy + sz * sz
                                         + tx * tx + ty * ty + tz * tz) / n;

        const double detR =
            R[0][0] * (R[1][1] * R[2][2] - R[1][2] * R[2][1])
          - R[0][1] * (R[1][0] * R[2][2] - R[1][2] * R[2][0])
          + R[0][2] * (R[1][0] * R[2][1] - R[1][1] * R[2][0]);

        double A00 = R[0][0]*R[0][0] + R[1][0]*R[1][0] + R[2][0]*R[2][0];
        double A11 = R[0][1]*R[0][1] + R[1][1]*R[1][1] + R[2][1]*R[2][1];
        double A22 = R[0][2]*R[0][2] + R[1][2]*R[1][2] + R[2][2]*R[2][2];
        double A01 = R[0][0]*R[0][1] + R[1][0]*R[1][1] + R[2][0]*R[2][1];
        double A02 = R[0][0]*R[0][2] + R[1][0]*R[1][2] + R[2][0]*R[2][2];
        double A12 = R[0][1]*R[0][2] + R[1][1]*R[1][2] + R[2][1]*R[2][2];

        double e0, e1, e2;  // descending
        const double p1 = A01*A01 + A02*A02 + A12*A12;
        if (p1 < 1e-30) {
            e0 = A00; e1 = A11; e2 = A22;
            double tmp;
            if (e0 < e1) { tmp = e0; e0 = e1; e1 = tmp; }
            if (e1 < e2) { tmp = e1; e1 = e2; e2 = tmp; }
            if (e0 < e1) { tmp = e0; e0 = e1; e1 = tmp; }
        } else {
            const double q  = (A00 + A11 + A22) / 3.0;
            const double b00 = A00 - q, b11 = A11 - q, b22 = A22 - q;
            const double p2 = b00*b00 + b11*b11 + b22*b22 + 2.0 * p1;
            const double p  = sqrt(p2 / 6.0);
            const double ip = 1.0 / p;
            const double B00 = b00*ip, B11 = b11*ip, B22 = b22*ip;
            const double B01 = A01*ip, B02 = A02*ip, B12 = A12*ip;
            double r = 0.5 * (B00 * (B11 * B22 - B12 * B12)
                            - B01 * (B01 * B22 - B12 * B02)
                            + B02 * (B01 * B12 - B11 * B02));
            if (r < -1.0) r = -1.0;
            if (r >  1.0) r =  1.0;
            const double phi = acos(r) / 3.0;
            e0 = q + 2.0 * p * cos(phi);
            e2 = q + 2.0 * p * cos(phi + 2.0943951023931953);  // +2pi/3
            e1 = 3.0 * q - e0 - e2;
        }

        const double S0 = sqrt(e0 > 0.0 ? e0 : 0.0);
        const double S1 = sqrt(e1 > 0.0 ? e1 : 0.0);
        const double S2 = sqrt(e2 > 0.0 ? e2 : 0.0);
        const double dsgn = (detR > 0.0) ? 1.0 : ((detR < 0.0) ? -1.0 : 0.0);
        const double trace_opt = S0 + S1 + dsgn * S2;

        double msd = (sq - 2.0 * trace_opt) / n;
        if (msd < 0.0) msd = 0.0;
        out[b] = (float)sqrt(msd);
    }
}

extern "C" void kernel_launch(void* const* d_in, const int* in_sizes, int n_in,
                              void* d_out, int out_size, void* d_ws, size_t ws_size,
                              hipStream_t stream) {
    const float* inp = (const float*)d_in[0];
    const float* tgt = (const float*)d_in[1];
    const int* num_atoms = (const int*)d_in[2];
    float* out = (float*)d_out;

    const int B = in_sizes[0] / (3 * NATOMS);
    const int blocks = (B + WPB - 1) / WPB;
    kabsch_rmsd_kernel<<<blocks, TPB, 0, stream>>>(inp, tgt, num_atoms, out, B);
}